// Round 3
// baseline (138.934 us; speedup 1.0000x reference)
//
#include <hip/hip_runtime.h>

typedef unsigned int u32;
typedef unsigned short u16;
typedef __attribute__((ext_vector_type(8))) short short8;
typedef __attribute__((ext_vector_type(4))) float f32x4;

#define LSEQ 2048
#define DM 1024
#define HWIN 128

__device__ __forceinline__ u16 f2bf(float f) {
  union { float f; u32 u; } v; v.f = f;
  u32 r = v.u + 0x7FFFu + ((v.u >> 16) & 1u);
  return (u16)(r >> 16);
}
__device__ __forceinline__ u32 packbf(float lo, float hi) {
  return (u32)f2bf(lo) | ((u32)f2bf(hi) << 16);
}

typedef __attribute__((address_space(3))) u32 lds_u32;
typedef __attribute__((address_space(1))) const u32 glob_u32;
__device__ __forceinline__ void g2lds16(const void* g, void* l) {
  __builtin_amdgcn_global_load_lds((glob_u32*)g, (lds_u32*)l, 16, 0, 0);
}

// ------------- LayerNorm (blocks 0..4095) + weight casts (4096..8191), one launch -------------
__global__ __launch_bounds__(256) void ln_cvt_kernel(const float* __restrict__ x,
                                                     const float* __restrict__ gamma,
                                                     const float* __restrict__ beta,
                                                     u16* __restrict__ xn,
                                                     const float* __restrict__ wqi,
                                                     const float* __restrict__ woi,
                                                     u16* __restrict__ wq,
                                                     u16* __restrict__ wo) {
  int blk = blockIdx.x;
  int t = threadIdx.x;
  if (blk >= 4096) {
    const float* in; u16* out; int i;
    if (blk < 7168) { in = wqi; out = wq; i = (blk - 4096) * 256 + t; }
    else            { in = woi; out = wo; i = (blk - 7168) * 256 + t; }
    float4 v = ((const float4*)in)[i];
    u32* dst = (u32*)out + i * 2;
    dst[0] = packbf(v.x, v.y);
    dst[1] = packbf(v.z, v.w);
    return;
  }
  int r = blk;
  const float4* xr = (const float4*)(x + (size_t)r * DM);
  float4 v = xr[t];
  float s = v.x + v.y + v.z + v.w;
  float s2 = v.x * v.x + v.y * v.y + v.z * v.z + v.w * v.w;
#pragma unroll
  for (int o = 32; o; o >>= 1) { s += __shfl_xor(s, o); s2 += __shfl_xor(s2, o); }
  __shared__ float ws1[4], ws2[4];
  if ((t & 63) == 0) { ws1[t >> 6] = s; ws2[t >> 6] = s2; }
  __syncthreads();
  s = ws1[0] + ws1[1] + ws1[2] + ws1[3];
  s2 = ws2[0] + ws2[1] + ws2[2] + ws2[3];
  float mu = s * (1.0f / DM);
  float var = s2 * (1.0f / DM) - mu * mu;
  float rs = rsqrtf(var + 1e-5f);
  float4 g = ((const float4*)gamma)[t];
  float4 b = ((const float4*)beta)[t];
  u32 lo = packbf((v.x - mu) * rs * g.x + b.x, (v.y - mu) * rs * g.y + b.y);
  u32 hi = packbf((v.z - mu) * rs * g.z + b.z, (v.w - mu) * rs * g.w + b.w);
  u32* dst = (u32*)(xn + (size_t)r * DM) + t * 2;
  dst[0] = lo; dst[1] = hi;
}

// ---- stage one 128x64 bf16 tile into LDS (source-side XOR swizzle, rule #21) ----
__device__ __forceinline__ void stage_tile(const u16* __restrict__ G, int gr0, int K,
                                           int k0, u16* lbuf, int tid, int w) {
#pragma unroll
  for (int j = 0; j < 4; ++j) {
    int rp = j * 32 + (tid >> 3);
    int ce = ((tid & 7) ^ (rp & 7)) * 8;
    g2lds16(G + (size_t)(gr0 + rp) * K + k0 + ce, lbuf + j * 2048 + w * 512);
  }
}

// ---------------- GEMM C = A @ B^T, 128x128 tile, BK=64, 2-phase dbuf ----------------
template <int MODE>
__global__ __launch_bounds__(256) void gemm_bt(const u16* __restrict__ Ag,
                                               const u16* __restrict__ Bg,
                                               int K, int NB,
                                               u16* __restrict__ qk_out,
                                               u16* __restrict__ vt_out,
                                               const float* __restrict__ resid,
                                               float* __restrict__ out) {
  __shared__ __align__(16) u16 sm[32768];
  int tid = threadIdx.x;
  int w = tid >> 6, l = tid & 63;
  int lg = l >> 4, li = l & 15;
  int bm = blockIdx.x / NB, bn = blockIdx.x % NB;
  int wr = w >> 1, wc = w & 1;
  f32x4 acc[4][4];
#pragma unroll
  for (int m = 0; m < 4; ++m)
#pragma unroll
    for (int n = 0; n < 4; ++n) acc[m][n] = (f32x4){0.f, 0.f, 0.f, 0.f};

  int nt = K >> 6;
  stage_tile(Ag, bm * 128, K, 0, sm, tid, w);
  stage_tile(Bg, bn * 128, K, 0, sm + 8192, tid, w);
  asm volatile("s_waitcnt vmcnt(0)" ::: "memory");
  __builtin_amdgcn_s_barrier();
  asm volatile("" ::: "memory");

  int cur = 0;
  for (int t = 0; t < nt; ++t) {
    if (t + 1 < nt) {
      stage_tile(Ag, bm * 128, K, (t + 1) << 6, sm + (cur ^ 1) * 16384, tid, w);
      stage_tile(Bg, bn * 128, K, (t + 1) << 6, sm + (cur ^ 1) * 16384 + 8192, tid, w);
    }
    const u16* Ab = sm + cur * 16384;
    const u16* Bb = Ab + 8192;
#pragma unroll
    for (int ks = 0; ks < 2; ++ks) {
      short8 af[4], bf4[4];
#pragma unroll
      for (int m = 0; m < 4; ++m)
        af[m] = *(const short8*)&Ab[(wr * 64 + m * 16 + li) * 64 + (((lg + ks * 4) ^ (li & 7)) * 8)];
#pragma unroll
      for (int n = 0; n < 4; ++n)
        bf4[n] = *(const short8*)&Bb[(wc * 64 + n * 16 + li) * 64 + (((lg + ks * 4) ^ (li & 7)) * 8)];
#pragma unroll
      for (int m = 0; m < 4; ++m)
#pragma unroll
        for (int n = 0; n < 4; ++n)
          acc[m][n] = __builtin_amdgcn_mfma_f32_16x16x32_bf16(af[m], bf4[n], acc[m][n], 0, 0, 0);
    }
    asm volatile("s_waitcnt vmcnt(0)" ::: "memory");
    __builtin_amdgcn_s_barrier();
    asm volatile("" ::: "memory");
    cur ^= 1;
  }

  int colbase = bn * 128 + wc * 64;
  int rowbase = bm * 128 + wr * 64;
#pragma unroll
  for (int m = 0; m < 4; ++m) {
    int row = rowbase + m * 16 + lg * 4;
#pragma unroll
    for (int n = 0; n < 4; ++n) {
      int col = colbase + n * 16 + li;
      if (MODE == 0) {
        if (colbase < 2048) {
#pragma unroll
          for (int r = 0; r < 4; ++r)
            qk_out[(size_t)(row + r) * 2048 + col] = f2bf(acc[m][n][r]);
        } else {
          int b = row >> 11;
          int hdcol = col - 2048;
          size_t idx = ((size_t)b * 1024 + hdcol) * 2048 + (row & 2047);
          u32* d = (u32*)&vt_out[idx];
          d[0] = packbf(acc[m][n][0], acc[m][n][1]);
          d[1] = packbf(acc[m][n][2], acc[m][n][3]);
        }
      } else {
#pragma unroll
        for (int r = 0; r < 4; ++r) {
          size_t idx = (size_t)(row + r) * 1024 + col;
          out[idx] = resid[idx] + acc[m][n][r];
        }
      }
    }
  }
}

// ---------------- banded attention, swapped S^T = mfma(K, Q), reg-dbuf pipeline ----------------
__device__ __forceinline__ void process_chunk(
    short8 k00, short8 k01, short8 k10, short8 k11,
    short8 v0, short8 v1, short8 v2, short8 v3,
    short8 qf0, short8 qf1,
    int kb, int qw, int q, int lg, int sg0, int sg1,
    float& mrun, float& lsum, f32x4& o0, f32x4& o1, f32x4& o2, f32x4& o3) {
  const float SC = 0.125f * 1.44269504088896f;  // 1/sqrt(64) * log2(e)
  f32x4 c0 = {0,0,0,0}, c1 = {0,0,0,0};
  c0 = __builtin_amdgcn_mfma_f32_16x16x32_bf16(k00, qf0, c0, 0, 0, 0);
  c0 = __builtin_amdgcn_mfma_f32_16x16x32_bf16(k01, qf1, c0, 0, 0, 0);
  c1 = __builtin_amdgcn_mfma_f32_16x16x32_bf16(k10, qf0, c1, 0, 0, 0);
  c1 = __builtin_amdgcn_mfma_f32_16x16x32_bf16(k11, qf1, c1, 0, 0, 0);

  float t[8];
  bool interior = (kb >= qw + 15 - HWIN) && (kb + 31 <= qw + HWIN);
  if (interior) {
#pragma unroll
    for (int r = 0; r < 4; ++r) { t[r] = c0[r] * SC; t[r + 4] = c1[r] * SC; }
  } else {
#pragma unroll
    for (int r = 0; r < 4; ++r) {
      int key0 = kb + lg * 4 + r;
      int key1 = key0 + 16;
      int d0 = key0 - q, d1 = key1 - q;
      t[r]     = (d0 >= -HWIN && d0 <= HWIN) ? c0[r] * SC : -__builtin_inff();
      t[r + 4] = (d1 >= -HWIN && d1 <= HWIN) ? c1[r] * SC : -__builtin_inff();
    }
  }
  float mA = fmaxf(fmaxf(t[0], t[1]), fmaxf(t[2], t[3]));
  float mB = fmaxf(fmaxf(t[4], t[5]), fmaxf(t[6], t[7]));
  float mc = fmaxf(mA, mB);
  mc = fmaxf(mc, __shfl_xor(mc, 16));
  mc = fmaxf(mc, __shfl_xor(mc, 32));

  float p[8];
  if (__all(mc <= mrun + 8.0f)) {
    // defer-max (T13): skip O-rescale; P bounded by e^8, bf16-safe; lsum per-lane partial
    float s0 = 0.f;
#pragma unroll
    for (int i = 0; i < 8; ++i) { p[i] = __builtin_amdgcn_exp2f(t[i] - mrun); s0 += p[i]; }
    lsum += s0;
  } else {
    float mn = fmaxf(mrun, mc);
    float corr = __builtin_amdgcn_exp2f(mrun - mn);
    float s0 = 0.f;
#pragma unroll
    for (int i = 0; i < 8; ++i) { p[i] = __builtin_amdgcn_exp2f(t[i] - mn); s0 += p[i]; }
    lsum = lsum * corr + s0;
    mrun = mn;
    o0 *= corr; o1 *= corr; o2 *= corr; o3 *= corr;
  }

  // P: C layout (keys 4*lg+r) -> B-frag layout (keys 8*lg+j), 8 bpermutes
  u32 a0 = packbf(p[0], p[1]);
  u32 a1 = packbf(p[2], p[3]);
  u32 b0 = packbf(p[4], p[5]);
  u32 b1 = packbf(p[6], p[7]);
  u32 w0 = (u32)__shfl((int)a0, sg0), w1 = (u32)__shfl((int)a1, sg0);
  u32 w2 = (u32)__shfl((int)a0, sg1), w3 = (u32)__shfl((int)a1, sg1);
  u32 x0 = (u32)__shfl((int)b0, sg0), x1 = (u32)__shfl((int)b1, sg0);
  u32 x2 = (u32)__shfl((int)b0, sg1), x3 = (u32)__shfl((int)b1, sg1);
  bool lohalf = lg < 2;
  union { u32 u[4]; short8 s; } pf;
  pf.u[0] = lohalf ? w0 : x0;
  pf.u[1] = lohalf ? w1 : x1;
  pf.u[2] = lohalf ? w2 : x2;
  pf.u[3] = lohalf ? w3 : x3;

  o0 = __builtin_amdgcn_mfma_f32_16x16x32_bf16(v0, pf.s, o0, 0, 0, 0);
  o1 = __builtin_amdgcn_mfma_f32_16x16x32_bf16(v1, pf.s, o1, 0, 0, 0);
  o2 = __builtin_amdgcn_mfma_f32_16x16x32_bf16(v2, pf.s, o2, 0, 0, 0);
  o3 = __builtin_amdgcn_mfma_f32_16x16x32_bf16(v3, pf.s, o3, 0, 0, 0);
}

// Issue all 8 K+V loads for a chunk into named regs (static buffers; rule #20)
#define LOADKV(P, kb)                                                        \
  do {                                                                       \
    const u16* kp0_ = kbase + (size_t)((kb) + li) * 2048;                    \
    const u16* kp1_ = kp0_ + (size_t)16 * 2048;                              \
    P##k00 = *(const short8*)kp0_;                                           \
    P##k01 = *(const short8*)(kp0_ + 32);                                    \
    P##k10 = *(const short8*)kp1_;                                           \
    P##k11 = *(const short8*)(kp1_ + 32);                                    \
    const u16* vp_ = vbase + (kb) + lg * 8;                                  \
    P##v0 = *(const short8*)vp_;                                             \
    P##v1 = *(const short8*)(vp_ + (size_t)16 * 2048);                       \
    P##v2 = *(const short8*)(vp_ + (size_t)32 * 2048);                       \
    P##v3 = *(const short8*)(vp_ + (size_t)48 * 2048);                       \
  } while (0)

#define PROC(P, kb)                                                          \
  process_chunk(P##k00, P##k01, P##k10, P##k11, P##v0, P##v1, P##v2, P##v3,  \
                qf0, qf1, (kb), qw, q, lg, sg0, sg1, mrun, lsum, o0, o1, o2, o3)

__global__ __launch_bounds__(256, 4) void attn_kernel(const u16* __restrict__ qk,
                                                      const u16* __restrict__ vt,
                                                      u16* __restrict__ ato) {
  int blk = blockIdx.x;
  int bh = blk >> 5;
  int qblk = blk & 31;
  int b = bh >> 4, h = bh & 15;
  int tid = threadIdx.x;
  int w = tid >> 6, l = tid & 63;
  int lg = l >> 4, li = l & 15;
  int qw = qblk * 64 + w * 16;
  int q = qw + li;
  int sg0 = (((2 * lg) & 3) << 4) + li;
  int sg1 = (((2 * lg + 1) & 3) << 4) + li;

  const u16* qbase = qk + (size_t)(b * 2048 + q) * 2048 + h * 64 + lg * 8;
  short8 qf0 = *(const short8*)qbase;
  short8 qf1 = *(const short8*)(qbase + 32);

  const u16* kbase = qk + (size_t)b * 2048 * 2048 + 1024 + h * 64 + lg * 8;
  const u16* vbase = vt + (size_t)(bh * 64 + li) * 2048;

  f32x4 o0 = {0,0,0,0}, o1 = {0,0,0,0}, o2 = {0,0,0,0}, o3 = {0,0,0,0};
  float mrun = -1e30f, lsum = 0.f;

  int lo = qw - HWIN; if (lo < 0) lo = 0;
  int hi = qw + 15 + HWIN; if (hi > LSEQ - 1) hi = LSEQ - 1;
  int kb0 = lo & ~31;
  int n = ((hi - kb0) >> 5) + 1;  // 32-key chunks; loop bounds keep all addrs in-range

  short8 Ak00, Ak01, Ak10, Ak11, Av0, Av1, Av2, Av3;
  short8 Bk00, Bk01, Bk10, Bk11, Bv0, Bv1, Bv2, Bv3;

  LOADKV(A, kb0);
  int c = 0;
  for (; c + 2 <= n; c += 2) {
    int kb = kb0 + (c << 5);
    LOADKV(B, kb + 32);            // prefetch next chunk (in flight across PROC(A))
    PROC(A, kb);                   // PV waits A-regs -> vmcnt leaves B loads pending
    if (c + 2 < n) LOADKV(A, kb + 64);
    PROC(B, kb + 32);
  }
  if (c < n) PROC(A, kb0 + (c << 5));

  lsum += __shfl_xor(lsum, 16);
  lsum += __shfl_xor(lsum, 32);
  float inv = 1.0f / lsum;
  u16* orow = ato + (size_t)(b * 2048 + q) * 1024 + h * 64 + lg * 4;
  *(u32*)(orow +  0) = packbf(o0[0] * inv, o0[1] * inv);
  *(u32*)(orow +  2) = packbf(o0[2] * inv, o0[3] * inv);
  *(u32*)(orow + 16) = packbf(o1[0] * inv, o1[1] * inv);
  *(u32*)(orow + 18) = packbf(o1[2] * inv, o1[3] * inv);
  *(u32*)(orow + 32) = packbf(o2[0] * inv, o2[1] * inv);
  *(u32*)(orow + 34) = packbf(o2[2] * inv, o2[3] * inv);
  *(u32*)(orow + 48) = packbf(o3[0] * inv, o3[1] * inv);
  *(u32*)(orow + 50) = packbf(o3[2] * inv, o3[3] * inv);
}

extern "C" void kernel_launch(void* const* d_in, const int* in_sizes, int n_in,
                              void* d_out, int out_size, void* d_ws, size_t ws_size,
                              hipStream_t stream) {
  const float* x     = (const float*)d_in[0];
  const float* w_qkv = (const float*)d_in[1];
  const float* w_out = (const float*)d_in[2];
  const float* gamma = (const float*)d_in[3];
  const float* beta  = (const float*)d_in[4];
  float* out = (float*)d_out;
  char* ws = (char*)d_ws;

  u16* xn  = (u16*)(ws);              //  8 MB  [4096][1024] bf16
  u16* wq  = (u16*)(ws + 8388608);    //  6 MB  [3072][1024] bf16
  u16* wo  = (u16*)(ws + 14680064);   //  2 MB  [1024][1024] bf16
  u16* qkb = (u16*)(ws + 16777216);   // 16 MB  [4096][2048] bf16 (Q|K)
  u16* vt  = (u16*)(ws + 33554432);   //  8 MB  [2][1024][2048] bf16 (V^T)
  u16* ao  = (u16*)(ws + 41943040);   //  8 MB  [4096][1024] bf16 attn out

  ln_cvt_kernel<<<8192, 256, 0, stream>>>(x, gamma, beta, xn, w_qkv, w_out, wq, wo);
  gemm_bt<0><<<32 * 24, 256, 0, stream>>>(xn, wq, 1024, 24, qkb, vt, nullptr, nullptr);
  attn_kernel<<<32 * 32, 256, 0, stream>>>(qkb, vt, ao);
  gemm_bt<1><<<32 * 8, 256, 0, stream>>>(ao, wo, 1024, 8, nullptr, nullptr, x, out);
}

// Round 5
// 105.547 us; speedup vs baseline: 1.3163x; 1.3163x over previous
//
#include <hip/hip_runtime.h>

typedef unsigned int u32;
typedef unsigned short u16;
typedef __attribute__((ext_vector_type(8))) short short8;
typedef __attribute__((ext_vector_type(4))) float f32x4;

#define LSEQ 2048
#define DM 1024
#define HWIN 128

__device__ __forceinline__ u16 f2bf(float f) {
  union { float f; u32 u; } v; v.f = f;
  u32 r = v.u + 0x7FFFu + ((v.u >> 16) & 1u);
  return (u16)(r >> 16);
}
__device__ __forceinline__ u32 packbf(float lo, float hi) {
  return (u32)f2bf(lo) | ((u32)f2bf(hi) << 16);
}

typedef __attribute__((address_space(3))) u32 lds_u32;
typedef __attribute__((address_space(1))) const u32 glob_u32;
__device__ __forceinline__ void g2lds16(const void* g, void* l) {
  __builtin_amdgcn_global_load_lds((glob_u32*)g, (lds_u32*)l, 16, 0, 0);
}

// ------------- LayerNorm (blocks 0..4095) + weight casts (4096..8191), one launch -------------
__global__ __launch_bounds__(256) void ln_cvt_kernel(const float* __restrict__ x,
                                                     const float* __restrict__ gamma,
                                                     const float* __restrict__ beta,
                                                     u16* __restrict__ xn,
                                                     const float* __restrict__ wqi,
                                                     const float* __restrict__ woi,
                                                     u16* __restrict__ wq,
                                                     u16* __restrict__ wo) {
  int blk = blockIdx.x;
  int t = threadIdx.x;
  if (blk >= 4096) {
    const float* in; u16* out; int i;
    if (blk < 7168) { in = wqi; out = wq; i = (blk - 4096) * 256 + t; }
    else            { in = woi; out = wo; i = (blk - 7168) * 256 + t; }
    float4 v = ((const float4*)in)[i];
    u32* dst = (u32*)out + i * 2;
    dst[0] = packbf(v.x, v.y);
    dst[1] = packbf(v.z, v.w);
    return;
  }
  int r = blk;
  const float4* xr = (const float4*)(x + (size_t)r * DM);
  float4 v = xr[t];
  float s = v.x + v.y + v.z + v.w;
  float s2 = v.x * v.x + v.y * v.y + v.z * v.z + v.w * v.w;
#pragma unroll
  for (int o = 32; o; o >>= 1) { s += __shfl_xor(s, o); s2 += __shfl_xor(s2, o); }
  __shared__ float ws1[4], ws2[4];
  if ((t & 63) == 0) { ws1[t >> 6] = s; ws2[t >> 6] = s2; }
  __syncthreads();
  s = ws1[0] + ws1[1] + ws1[2] + ws1[3];
  s2 = ws2[0] + ws2[1] + ws2[2] + ws2[3];
  float mu = s * (1.0f / DM);
  float var = s2 * (1.0f / DM) - mu * mu;
  float rs = rsqrtf(var + 1e-5f);
  float4 g = ((const float4*)gamma)[t];
  float4 b = ((const float4*)beta)[t];
  u32 lo = packbf((v.x - mu) * rs * g.x + b.x, (v.y - mu) * rs * g.y + b.y);
  u32 hi = packbf((v.z - mu) * rs * g.z + b.z, (v.w - mu) * rs * g.w + b.w);
  u32* dst = (u32*)(xn + (size_t)r * DM) + t * 2;
  dst[0] = lo; dst[1] = hi;
}

// ---- stage one 128x64 bf16 tile into LDS (source-side XOR swizzle, rule #21) ----
__device__ __forceinline__ void stage_tile(const u16* __restrict__ G, int gr0, int K,
                                           int k0, u16* lbuf, int tid, int w) {
#pragma unroll
  for (int j = 0; j < 4; ++j) {
    int rp = j * 32 + (tid >> 3);
    int ce = ((tid & 7) ^ (rp & 7)) * 8;
    g2lds16(G + (size_t)(gr0 + rp) * K + k0 + ce, lbuf + j * 2048 + w * 512);
  }
}

// ---------------- GEMM C = A @ B^T, 128x128 tile, BK=64, 2-phase dbuf ----------------
template <int MODE>
__global__ __launch_bounds__(256) void gemm_bt(const u16* __restrict__ Ag,
                                               const u16* __restrict__ Bg,
                                               int K, int NB,
                                               u16* __restrict__ qk_out,
                                               u16* __restrict__ vt_out,
                                               const float* __restrict__ resid,
                                               float* __restrict__ out) {
  __shared__ __align__(16) u16 sm[32768];
  int tid = threadIdx.x;
  int w = tid >> 6, l = tid & 63;
  int lg = l >> 4, li = l & 15;
  int bm = blockIdx.x / NB, bn = blockIdx.x % NB;
  int wr = w >> 1, wc = w & 1;
  f32x4 acc[4][4];
#pragma unroll
  for (int m = 0; m < 4; ++m)
#pragma unroll
    for (int n = 0; n < 4; ++n) acc[m][n] = (f32x4){0.f, 0.f, 0.f, 0.f};

  int nt = K >> 6;
  stage_tile(Ag, bm * 128, K, 0, sm, tid, w);
  stage_tile(Bg, bn * 128, K, 0, sm + 8192, tid, w);
  asm volatile("s_waitcnt vmcnt(0)" ::: "memory");
  __builtin_amdgcn_s_barrier();
  asm volatile("" ::: "memory");

  int cur = 0;
  for (int t = 0; t < nt; ++t) {
    if (t + 1 < nt) {
      stage_tile(Ag, bm * 128, K, (t + 1) << 6, sm + (cur ^ 1) * 16384, tid, w);
      stage_tile(Bg, bn * 128, K, (t + 1) << 6, sm + (cur ^ 1) * 16384 + 8192, tid, w);
    }
    const u16* Ab = sm + cur * 16384;
    const u16* Bb = Ab + 8192;
#pragma unroll
    for (int ks = 0; ks < 2; ++ks) {
      short8 af[4], bf4[4];
#pragma unroll
      for (int m = 0; m < 4; ++m)
        af[m] = *(const short8*)&Ab[(wr * 64 + m * 16 + li) * 64 + (((lg + ks * 4) ^ (li & 7)) * 8)];
#pragma unroll
      for (int n = 0; n < 4; ++n)
        bf4[n] = *(const short8*)&Bb[(wc * 64 + n * 16 + li) * 64 + (((lg + ks * 4) ^ (li & 7)) * 8)];
#pragma unroll
      for (int m = 0; m < 4; ++m)
#pragma unroll
        for (int n = 0; n < 4; ++n)
          acc[m][n] = __builtin_amdgcn_mfma_f32_16x16x32_bf16(af[m], bf4[n], acc[m][n], 0, 0, 0);
    }
    asm volatile("s_waitcnt vmcnt(0)" ::: "memory");
    __builtin_amdgcn_s_barrier();
    asm volatile("" ::: "memory");
    cur ^= 1;
  }

  int colbase = bn * 128 + wc * 64;
  int rowbase = bm * 128 + wr * 64;
#pragma unroll
  for (int m = 0; m < 4; ++m) {
    int row = rowbase + m * 16 + lg * 4;
#pragma unroll
    for (int n = 0; n < 4; ++n) {
      int col = colbase + n * 16 + li;
      if (MODE == 0) {
        if (colbase < 2048) {
#pragma unroll
          for (int r = 0; r < 4; ++r)
            qk_out[(size_t)(row + r) * 2048 + col] = f2bf(acc[m][n][r]);
        } else {
          int b = row >> 11;
          int hdcol = col - 2048;
          size_t idx = ((size_t)b * 1024 + hdcol) * 2048 + (row & 2047);
          u32* d = (u32*)&vt_out[idx];
          d[0] = packbf(acc[m][n][0], acc[m][n][1]);
          d[1] = packbf(acc[m][n][2], acc[m][n][3]);
        }
      } else {
#pragma unroll
        for (int r = 0; r < 4; ++r) {
          size_t idx = (size_t)(row + r) * 1024 + col;
          out[idx] = resid[idx] + acc[m][n][r];
        }
      }
    }
  }
}

// ---------------- banded attention: wave-pair split-K + LDS combine ----------------
// grid = 32 (b,h) * 64 qblocks of 32 queries; block = 4 waves = 2 pairs.
// Pair handles 16 queries; half 0 takes even chunks, half 1 odd chunks.
__global__ __launch_bounds__(256) void attn_kernel(const u16* __restrict__ qk,
                                                   const u16* __restrict__ vt,
                                                   u16* __restrict__ ato) {
  int blk = blockIdx.x;
  int bh = blk >> 6;
  int qblk = blk & 63;
  int b = bh >> 4, h = bh & 15;
  int tid = threadIdx.x;
  int w = tid >> 6, l = tid & 63;
  int pair = w >> 1, half = w & 1;
  int lg = l >> 4, li = l & 15;
  int qw = qblk * 32 + pair * 16;
  int q = qw + li;
  int sg0 = (((2 * lg) & 3) << 4) + li;
  int sg1 = (((2 * lg + 1) & 3) << 4) + li;

  const u16* qbase = qk + (size_t)(b * 2048 + q) * 2048 + h * 64 + lg * 8;
  short8 qf0 = *(const short8*)qbase;
  short8 qf1 = *(const short8*)(qbase + 32);

  const u16* kbase = qk + (size_t)b * 2048 * 2048 + 1024 + h * 64 + lg * 8;
  const u16* vbase = vt + (size_t)(bh * 64 + li) * 2048;

  f32x4 o0 = {0,0,0,0}, o1 = {0,0,0,0}, o2 = {0,0,0,0}, o3 = {0,0,0,0};
  float mrun = -1e30f, lsum = 0.f;

  int lo = qw - HWIN; if (lo < 0) lo = 0;
  int hi = qw + 15 + HWIN; if (hi > LSEQ - 1) hi = LSEQ - 1;
  int kb0 = lo & ~31;
  int n = ((hi - kb0) >> 5) + 1;  // 5..9 chunks; each half gets >=2
  const float SC = 0.125f * 1.44269504088896f;  // 1/sqrt(64) * log2(e)

  for (int c = half; c < n; c += 2) {
    int kb = kb0 + (c << 5);
    const u16* kp0 = kbase + (size_t)(kb + li) * 2048;
    const u16* kp1 = kp0 + (size_t)16 * 2048;
    short8 k00 = *(const short8*)kp0;
    short8 k01 = *(const short8*)(kp0 + 32);
    short8 k10 = *(const short8*)kp1;
    short8 k11 = *(const short8*)(kp1 + 32);
    f32x4 c0 = {0,0,0,0}, c1 = {0,0,0,0};
    c0 = __builtin_amdgcn_mfma_f32_16x16x32_bf16(k00, qf0, c0, 0, 0, 0);
    c0 = __builtin_amdgcn_mfma_f32_16x16x32_bf16(k01, qf1, c0, 0, 0, 0);
    c1 = __builtin_amdgcn_mfma_f32_16x16x32_bf16(k10, qf0, c1, 0, 0, 0);
    c1 = __builtin_amdgcn_mfma_f32_16x16x32_bf16(k11, qf1, c1, 0, 0, 0);

    float t[8];
    bool interior = (kb >= qw + 15 - HWIN) && (kb + 31 <= qw + HWIN);
    if (interior) {
#pragma unroll
      for (int r = 0; r < 4; ++r) { t[r] = c0[r] * SC; t[r + 4] = c1[r] * SC; }
    } else {
#pragma unroll
      for (int r = 0; r < 4; ++r) {
        int key0 = kb + lg * 4 + r;
        int key1 = key0 + 16;
        int d0 = key0 - q, d1 = key1 - q;
        t[r]     = (d0 >= -HWIN && d0 <= HWIN) ? c0[r] * SC : -__builtin_inff();
        t[r + 4] = (d1 >= -HWIN && d1 <= HWIN) ? c1[r] * SC : -__builtin_inff();
      }
    }
    float mA = fmaxf(fmaxf(t[0], t[1]), fmaxf(t[2], t[3]));
    float mB = fmaxf(fmaxf(t[4], t[5]), fmaxf(t[6], t[7]));
    float mc = fmaxf(mA, mB);
    mc = fmaxf(mc, __shfl_xor(mc, 16));
    mc = fmaxf(mc, __shfl_xor(mc, 32));   // per-query max (uniform over the 4 lg replicas)

    float p[8];
    if (__all(mc <= mrun + 8.0f)) {
      // defer-max (T13): skip O-rescale; P bounded by 2^8, bf16-safe
      float s0 = 0.f;
#pragma unroll
      for (int i = 0; i < 8; ++i) { p[i] = __builtin_amdgcn_exp2f(t[i] - mrun); s0 += p[i]; }
      lsum += s0;
    } else {
      float mn = fmaxf(mrun, mc);
      float corr = __builtin_amdgcn_exp2f(mrun - mn);
      float s0 = 0.f;
#pragma unroll
      for (int i = 0; i < 8; ++i) { p[i] = __builtin_amdgcn_exp2f(t[i] - mn); s0 += p[i]; }
      lsum = lsum * corr + s0;
      mrun = mn;
      o0 *= corr; o1 *= corr; o2 *= corr; o3 *= corr;
    }

    // P: C layout (keys 4*lg+r) -> B-frag layout (keys 8*lg+j), 8 bpermutes
    u32 a0 = packbf(p[0], p[1]);
    u32 a1 = packbf(p[2], p[3]);
    u32 b0 = packbf(p[4], p[5]);
    u32 b1 = packbf(p[6], p[7]);
    u32 w0 = (u32)__shfl((int)a0, sg0), w1 = (u32)__shfl((int)a1, sg0);
    u32 w2 = (u32)__shfl((int)a0, sg1), w3 = (u32)__shfl((int)a1, sg1);
    u32 x0 = (u32)__shfl((int)b0, sg0), x1 = (u32)__shfl((int)b1, sg0);
    u32 x2 = (u32)__shfl((int)b0, sg1), x3 = (u32)__shfl((int)b1, sg1);
    bool lohalf = lg < 2;
    union { u32 u[4]; short8 s; } pf;
    pf.u[0] = lohalf ? w0 : x0;
    pf.u[1] = lohalf ? w1 : x1;
    pf.u[2] = lohalf ? w2 : x2;
    pf.u[3] = lohalf ? w3 : x3;

    const u16* vp = vbase + kb + lg * 8;
    short8 v0 = *(const short8*)(vp);
    short8 v1 = *(const short8*)(vp + (size_t)16 * 2048);
    short8 v2 = *(const short8*)(vp + (size_t)32 * 2048);
    short8 v3 = *(const short8*)(vp + (size_t)48 * 2048);
    o0 = __builtin_amdgcn_mfma_f32_16x16x32_bf16(v0, pf.s, o0, 0, 0, 0);
    o1 = __builtin_amdgcn_mfma_f32_16x16x32_bf16(v1, pf.s, o1, 0, 0, 0);
    o2 = __builtin_amdgcn_mfma_f32_16x16x32_bf16(v2, pf.s, o2, 0, 0, 0);
    o3 = __builtin_amdgcn_mfma_f32_16x16x32_bf16(v3, pf.s, o3, 0, 0, 0);
  }

  // ---- merge the two halves' online-softmax partials (PER QUERY, not per wave) ----
  lsum += __shfl_xor(lsum, 16);
  lsum += __shfl_xor(lsum, 32);   // per-query total, uniform over the 4 lg replicas

  __shared__ float ml[2][2][2][16];  // [pair][half][{m,l}][query li]
  __shared__ float olds[2][64][18];  // pad 18: max 2-way bank alias (free)
  if (l < 16) { ml[pair][half][0][li] = mrun; ml[pair][half][1][li] = lsum; }
  __syncthreads();
  float m0 = ml[pair][0][0][li], l0 = ml[pair][0][1][li];
  float m1 = ml[pair][1][0][li], l1 = ml[pair][1][1][li];
  float ms = fmaxf(m0, m1);
  float c0s = __builtin_amdgcn_exp2f(m0 - ms);
  float c1s = __builtin_amdgcn_exp2f(m1 - ms);
  float ltot = l0 * c0s + l1 * c1s;
  float myc = half ? c1s : c0s;
  o0 *= myc; o1 *= myc; o2 *= myc; o3 *= myc;

  if (half == 1) {
#pragma unroll
    for (int r = 0; r < 4; ++r) {
      olds[pair][ 0 + lg * 4 + r][li] = o0[r];
      olds[pair][16 + lg * 4 + r][li] = o1[r];
      olds[pair][32 + lg * 4 + r][li] = o2[r];
      olds[pair][48 + lg * 4 + r][li] = o3[r];
    }
  }
  __syncthreads();
  if (half == 0) {
#pragma unroll
    for (int r = 0; r < 4; ++r) {
      o0[r] += olds[pair][ 0 + lg * 4 + r][li];
      o1[r] += olds[pair][16 + lg * 4 + r][li];
      o2[r] += olds[pair][32 + lg * 4 + r][li];
      o3[r] += olds[pair][48 + lg * 4 + r][li];
    }
    float inv = 1.0f / ltot;
    u16* orow = ato + (size_t)(b * 2048 + q) * 1024 + h * 64 + lg * 4;
    *(u32*)(orow +  0) = packbf(o0[0] * inv, o0[1] * inv);
    *(u32*)(orow +  2) = packbf(o0[2] * inv, o0[3] * inv);
    *(u32*)(orow + 16) = packbf(o1[0] * inv, o1[1] * inv);
    *(u32*)(orow + 18) = packbf(o1[2] * inv, o1[3] * inv);
    *(u32*)(orow + 32) = packbf(o2[0] * inv, o2[1] * inv);
    *(u32*)(orow + 34) = packbf(o2[2] * inv, o2[3] * inv);
    *(u32*)(orow + 48) = packbf(o3[0] * inv, o3[1] * inv);
    *(u32*)(orow + 50) = packbf(o3[2] * inv, o3[3] * inv);
  }
}

extern "C" void kernel_launch(void* const* d_in, const int* in_sizes, int n_in,
                              void* d_out, int out_size, void* d_ws, size_t ws_size,
                              hipStream_t stream) {
  const float* x     = (const float*)d_in[0];
  const float* w_qkv = (const float*)d_in[1];
  const float* w_out = (const float*)d_in[2];
  const float* gamma = (const float*)d_in[3];
  const float* beta  = (const float*)d_in[4];
  float* out = (float*)d_out;
  char* ws = (char*)d_ws;

  u16* xn  = (u16*)(ws);              //  8 MB  [4096][1024] bf16
  u16* wq  = (u16*)(ws + 8388608);    //  6 MB  [3072][1024] bf16
  u16* wo  = (u16*)(ws + 14680064);   //  2 MB  [1024][1024] bf16
  u16* qkb = (u16*)(ws + 16777216);   // 16 MB  [4096][2048] bf16 (Q|K)
  u16* vt  = (u16*)(ws + 33554432);   //  8 MB  [2][1024][2048] bf16 (V^T)
  u16* ao  = (u16*)(ws + 41943040);   //  8 MB  [4096][1024] bf16 attn out

  ln_cvt_kernel<<<8192, 256, 0, stream>>>(x, gamma, beta, xn, w_qkv, w_out, wq, wo);
  gemm_bt<0><<<32 * 24, 256, 0, stream>>>(xn, wq, 1024, 24, qkb, vt, nullptr, nullptr);
  attn_kernel<<<32 * 64, 256, 0, stream>>>(qkb, vt, ao);
  gemm_bt<1><<<32 * 8, 256, 0, stream>>>(ao, wo, 1024, 8, nullptr, nullptr, x, out);
}

// Round 6
// 105.193 us; speedup vs baseline: 1.3208x; 1.0034x over previous
//
#include <hip/hip_runtime.h>

typedef unsigned int u32;
typedef unsigned short u16;
typedef __attribute__((ext_vector_type(8))) short short8;
typedef __attribute__((ext_vector_type(4))) float f32x4;

#define LSEQ 2048
#define DM 1024
#define HWIN 128

__device__ __forceinline__ u16 f2bf(float f) {
  union { float f; u32 u; } v; v.f = f;
  u32 r = v.u + 0x7FFFu + ((v.u >> 16) & 1u);
  return (u16)(r >> 16);
}
__device__ __forceinline__ u32 packbf(float lo, float hi) {
  return (u32)f2bf(lo) | ((u32)f2bf(hi) << 16);
}

typedef __attribute__((address_space(3))) u32 lds_u32;
typedef __attribute__((address_space(1))) const u32 glob_u32;
__device__ __forceinline__ void g2lds16(const void* g, void* l) {
  __builtin_amdgcn_global_load_lds((glob_u32*)g, (lds_u32*)l, 16, 0, 0);
}

// ------------- LayerNorm (blocks 0..4095) + weight casts (4096..8191), one launch -------------
__global__ __launch_bounds__(256) void ln_cvt_kernel(const float* __restrict__ x,
                                                     const float* __restrict__ gamma,
                                                     const float* __restrict__ beta,
                                                     u16* __restrict__ xn,
                                                     const float* __restrict__ wqi,
                                                     const float* __restrict__ woi,
                                                     u16* __restrict__ wq,
                                                     u16* __restrict__ wo) {
  int blk = blockIdx.x;
  int t = threadIdx.x;
  if (blk >= 4096) {
    const float* in; u16* out; int i;
    if (blk < 7168) { in = wqi; out = wq; i = (blk - 4096) * 256 + t; }
    else            { in = woi; out = wo; i = (blk - 7168) * 256 + t; }
    float4 v = ((const float4*)in)[i];
    u32* dst = (u32*)out + i * 2;
    dst[0] = packbf(v.x, v.y);
    dst[1] = packbf(v.z, v.w);
    return;
  }
  int r = blk;
  const float4* xr = (const float4*)(x + (size_t)r * DM);
  float4 v = xr[t];
  float s = v.x + v.y + v.z + v.w;
  float s2 = v.x * v.x + v.y * v.y + v.z * v.z + v.w * v.w;
#pragma unroll
  for (int o = 32; o; o >>= 1) { s += __shfl_xor(s, o); s2 += __shfl_xor(s2, o); }
  __shared__ float ws1[4], ws2[4];
  if ((t & 63) == 0) { ws1[t >> 6] = s; ws2[t >> 6] = s2; }
  __syncthreads();
  s = ws1[0] + ws1[1] + ws1[2] + ws1[3];
  s2 = ws2[0] + ws2[1] + ws2[2] + ws2[3];
  float mu = s * (1.0f / DM);
  float var = s2 * (1.0f / DM) - mu * mu;
  float rs = rsqrtf(var + 1e-5f);
  float4 g = ((const float4*)gamma)[t];
  float4 b = ((const float4*)beta)[t];
  u32 lo = packbf((v.x - mu) * rs * g.x + b.x, (v.y - mu) * rs * g.y + b.y);
  u32 hi = packbf((v.z - mu) * rs * g.z + b.z, (v.w - mu) * rs * g.w + b.w);
  u32* dst = (u32*)(xn + (size_t)r * DM) + t * 2;
  dst[0] = lo; dst[1] = hi;
}

// ---- stage one 128x64 bf16 tile into LDS (source-side XOR swizzle, rule #21) ----
__device__ __forceinline__ void stage_tile(const u16* __restrict__ G, int gr0, int K,
                                           int k0, u16* lbuf, int tid, int w) {
#pragma unroll
  for (int j = 0; j < 4; ++j) {
    int rp = j * 32 + (tid >> 3);
    int ce = ((tid & 7) ^ (rp & 7)) * 8;
    g2lds16(G + (size_t)(gr0 + rp) * K + k0 + ce, lbuf + j * 2048 + w * 512);
  }
}

// ---------------- GEMM C = A @ B^T, 128x128 tile, BK=64, 2-phase dbuf ----------------
template <int MODE>
__global__ __launch_bounds__(256) void gemm_bt(const u16* __restrict__ Ag,
                                               const u16* __restrict__ Bg,
                                               int K, int NB,
                                               u16* __restrict__ qk_out,
                                               u16* __restrict__ vt_out,
                                               const float* __restrict__ resid,
                                               float* __restrict__ out) {
  __shared__ __align__(16) u16 sm[32768];
  int tid = threadIdx.x;
  int w = tid >> 6, l = tid & 63;
  int lg = l >> 4, li = l & 15;
  int bm = blockIdx.x / NB, bn = blockIdx.x % NB;
  int wr = w >> 1, wc = w & 1;
  f32x4 acc[4][4];
#pragma unroll
  for (int m = 0; m < 4; ++m)
#pragma unroll
    for (int n = 0; n < 4; ++n) acc[m][n] = (f32x4){0.f, 0.f, 0.f, 0.f};

  int nt = K >> 6;
  stage_tile(Ag, bm * 128, K, 0, sm, tid, w);
  stage_tile(Bg, bn * 128, K, 0, sm + 8192, tid, w);
  asm volatile("s_waitcnt vmcnt(0)" ::: "memory");
  __builtin_amdgcn_s_barrier();
  asm volatile("" ::: "memory");

  int cur = 0;
  for (int t = 0; t < nt; ++t) {
    if (t + 1 < nt) {
      stage_tile(Ag, bm * 128, K, (t + 1) << 6, sm + (cur ^ 1) * 16384, tid, w);
      stage_tile(Bg, bn * 128, K, (t + 1) << 6, sm + (cur ^ 1) * 16384 + 8192, tid, w);
    }
    const u16* Ab = sm + cur * 16384;
    const u16* Bb = Ab + 8192;
#pragma unroll
    for (int ks = 0; ks < 2; ++ks) {
      short8 af[4], bf4[4];
#pragma unroll
      for (int m = 0; m < 4; ++m)
        af[m] = *(const short8*)&Ab[(wr * 64 + m * 16 + li) * 64 + (((lg + ks * 4) ^ (li & 7)) * 8)];
#pragma unroll
      for (int n = 0; n < 4; ++n)
        bf4[n] = *(const short8*)&Bb[(wc * 64 + n * 16 + li) * 64 + (((lg + ks * 4) ^ (li & 7)) * 8)];
#pragma unroll
      for (int m = 0; m < 4; ++m)
#pragma unroll
        for (int n = 0; n < 4; ++n)
          acc[m][n] = __builtin_amdgcn_mfma_f32_16x16x32_bf16(af[m], bf4[n], acc[m][n], 0, 0, 0);
    }
    asm volatile("s_waitcnt vmcnt(0)" ::: "memory");
    __builtin_amdgcn_s_barrier();
    asm volatile("" ::: "memory");
    cur ^= 1;
  }

  int colbase = bn * 128 + wc * 64;
  int rowbase = bm * 128 + wr * 64;
#pragma unroll
  for (int m = 0; m < 4; ++m) {
    int row = rowbase + m * 16 + lg * 4;
#pragma unroll
    for (int n = 0; n < 4; ++n) {
      int col = colbase + n * 16 + li;
      if (MODE == 0) {
        if (colbase < 2048) {
#pragma unroll
          for (int r = 0; r < 4; ++r)
            qk_out[(size_t)(row + r) * 2048 + col] = f2bf(acc[m][n][r]);
        } else {
          int b = row >> 11;
          int hdcol = col - 2048;
          size_t idx = ((size_t)b * 1024 + hdcol) * 2048 + (row & 2047);
          u32* d = (u32*)&vt_out[idx];
          d[0] = packbf(acc[m][n][0], acc[m][n][1]);
          d[1] = packbf(acc[m][n][2], acc[m][n][3]);
        }
      } else {
#pragma unroll
        for (int r = 0; r < 4; ++r) {
          size_t idx = (size_t)(row + r) * 1024 + col;
          out[idx] = resid[idx] + acc[m][n][r];
        }
      }
    }
  }
}

// ---------------- banded attention: wave-pair split-K + LDS combine ----------------
// grid = 2048 blocks; XCD-swizzled so all 64 q-blocks of one (b,h) share an XCD
// (T1: K/V slab 512 KB/head, 4 heads/XCD = 2 MB < 4 MB L2 -> L2-resident).
__global__ __launch_bounds__(256) void attn_kernel(const u16* __restrict__ qk,
                                                   const u16* __restrict__ vt,
                                                   u16* __restrict__ ato) {
  int blk0 = blockIdx.x;
  int xcd = blk0 & 7;           // dispatch round-robins blockIdx%8 across XCDs
  int j = blk0 >> 3;            // 0..255 within XCD
  int bh = xcd * 4 + (j & 3);   // 4 heads per XCD
  int qblk = j >> 2;            // 0..63
  int b = bh >> 4, h = bh & 15;
  int tid = threadIdx.x;
  int w = tid >> 6, l = tid & 63;
  int pair = w >> 1, half = w & 1;
  int lg = l >> 4, li = l & 15;
  int qw = qblk * 32 + pair * 16;
  int q = qw + li;
  int sg0 = (((2 * lg) & 3) << 4) + li;
  int sg1 = (((2 * lg + 1) & 3) << 4) + li;

  const u16* qbase = qk + (size_t)(b * 2048 + q) * 2048 + h * 64 + lg * 8;
  short8 qf0 = *(const short8*)qbase;
  short8 qf1 = *(const short8*)(qbase + 32);

  const u16* kbase = qk + (size_t)b * 2048 * 2048 + 1024 + h * 64 + lg * 8;
  const u16* vbase = vt + (size_t)(bh * 64 + li) * 2048;

  f32x4 o0 = {0,0,0,0}, o1 = {0,0,0,0}, o2 = {0,0,0,0}, o3 = {0,0,0,0};
  float mrun = -1e30f, lsum = 0.f;

  int lo = qw - HWIN; if (lo < 0) lo = 0;
  int hi = qw + 15 + HWIN; if (hi > LSEQ - 1) hi = LSEQ - 1;
  int kb0 = lo & ~31;
  int n = ((hi - kb0) >> 5) + 1;  // 5..9 chunks; each half gets >=2
  const float SC = 0.125f * 1.44269504088896f;  // 1/sqrt(64) * log2(e)

  for (int c = half; c < n; c += 2) {
    int kb = kb0 + (c << 5);
    const u16* kp0 = kbase + (size_t)(kb + li) * 2048;
    const u16* kp1 = kp0 + (size_t)16 * 2048;
    short8 k00 = *(const short8*)kp0;
    short8 k01 = *(const short8*)(kp0 + 32);
    short8 k10 = *(const short8*)kp1;
    short8 k11 = *(const short8*)(kp1 + 32);
    f32x4 c0 = {0,0,0,0}, c1 = {0,0,0,0};
    c0 = __builtin_amdgcn_mfma_f32_16x16x32_bf16(k00, qf0, c0, 0, 0, 0);
    c0 = __builtin_amdgcn_mfma_f32_16x16x32_bf16(k01, qf1, c0, 0, 0, 0);
    c1 = __builtin_amdgcn_mfma_f32_16x16x32_bf16(k10, qf0, c1, 0, 0, 0);
    c1 = __builtin_amdgcn_mfma_f32_16x16x32_bf16(k11, qf1, c1, 0, 0, 0);

    float t[8];
    bool interior = (kb >= qw + 15 - HWIN) && (kb + 31 <= qw + HWIN);
    if (interior) {
#pragma unroll
      for (int r = 0; r < 4; ++r) { t[r] = c0[r] * SC; t[r + 4] = c1[r] * SC; }
    } else {
#pragma unroll
      for (int r = 0; r < 4; ++r) {
        int key0 = kb + lg * 4 + r;
        int key1 = key0 + 16;
        int d0 = key0 - q, d1 = key1 - q;
        t[r]     = (d0 >= -HWIN && d0 <= HWIN) ? c0[r] * SC : -__builtin_inff();
        t[r + 4] = (d1 >= -HWIN && d1 <= HWIN) ? c1[r] * SC : -__builtin_inff();
      }
    }
    float mA = fmaxf(fmaxf(t[0], t[1]), fmaxf(t[2], t[3]));
    float mB = fmaxf(fmaxf(t[4], t[5]), fmaxf(t[6], t[7]));
    float mc = fmaxf(mA, mB);
    mc = fmaxf(mc, __shfl_xor(mc, 16));
    mc = fmaxf(mc, __shfl_xor(mc, 32));   // per-query max (uniform over the 4 lg replicas)

    float p[8];
    if (__all(mc <= mrun + 8.0f)) {
      // defer-max (T13): skip O-rescale; P bounded by 2^8, bf16-safe
      float s0 = 0.f;
#pragma unroll
      for (int i = 0; i < 8; ++i) { p[i] = __builtin_amdgcn_exp2f(t[i] - mrun); s0 += p[i]; }
      lsum += s0;
    } else {
      float mn = fmaxf(mrun, mc);
      float corr = __builtin_amdgcn_exp2f(mrun - mn);
      float s0 = 0.f;
#pragma unroll
      for (int i = 0; i < 8; ++i) { p[i] = __builtin_amdgcn_exp2f(t[i] - mn); s0 += p[i]; }
      lsum = lsum * corr + s0;
      mrun = mn;
      o0 *= corr; o1 *= corr; o2 *= corr; o3 *= corr;
    }

    // P: C layout (keys 4*lg+r) -> B-frag layout (keys 8*lg+j), 8 bpermutes
    u32 a0 = packbf(p[0], p[1]);
    u32 a1 = packbf(p[2], p[3]);
    u32 b0 = packbf(p[4], p[5]);
    u32 b1 = packbf(p[6], p[7]);
    u32 w0 = (u32)__shfl((int)a0, sg0), w1 = (u32)__shfl((int)a1, sg0);
    u32 w2 = (u32)__shfl((int)a0, sg1), w3 = (u32)__shfl((int)a1, sg1);
    u32 x0 = (u32)__shfl((int)b0, sg0), x1 = (u32)__shfl((int)b1, sg0);
    u32 x2 = (u32)__shfl((int)b0, sg1), x3 = (u32)__shfl((int)b1, sg1);
    bool lohalf = lg < 2;
    union { u32 u[4]; short8 s; } pf;
    pf.u[0] = lohalf ? w0 : x0;
    pf.u[1] = lohalf ? w1 : x1;
    pf.u[2] = lohalf ? w2 : x2;
    pf.u[3] = lohalf ? w3 : x3;

    const u16* vp = vbase + kb + lg * 8;
    short8 v0 = *(const short8*)(vp);
    short8 v1 = *(const short8*)(vp + (size_t)16 * 2048);
    short8 v2 = *(const short8*)(vp + (size_t)32 * 2048);
    short8 v3 = *(const short8*)(vp + (size_t)48 * 2048);
    o0 = __builtin_amdgcn_mfma_f32_16x16x32_bf16(v0, pf.s, o0, 0, 0, 0);
    o1 = __builtin_amdgcn_mfma_f32_16x16x32_bf16(v1, pf.s, o1, 0, 0, 0);
    o2 = __builtin_amdgcn_mfma_f32_16x16x32_bf16(v2, pf.s, o2, 0, 0, 0);
    o3 = __builtin_amdgcn_mfma_f32_16x16x32_bf16(v3, pf.s, o3, 0, 0, 0);
  }

  // ---- merge the two halves' online-softmax partials (per query) ----
  lsum += __shfl_xor(lsum, 16);
  lsum += __shfl_xor(lsum, 32);   // per-query total, uniform over the 4 lg replicas

  __shared__ float ml[2][2][2][16];  // [pair][half][{m,l}][query li]
  __shared__ float olds[2][64][18];  // pad 18: max 2-way bank alias (free)
  if (l < 16) { ml[pair][half][0][li] = mrun; ml[pair][half][1][li] = lsum; }
  __syncthreads();
  float m0 = ml[pair][0][0][li], l0 = ml[pair][0][1][li];
  float m1 = ml[pair][1][0][li], l1 = ml[pair][1][1][li];
  float ms = fmaxf(m0, m1);
  float c0s = __builtin_amdgcn_exp2f(m0 - ms);
  float c1s = __builtin_amdgcn_exp2f(m1 - ms);
  float ltot = l0 * c0s + l1 * c1s;
  float myc = half ? c1s : c0s;
  o0 *= myc; o1 *= myc; o2 *= myc; o3 *= myc;

  if (half == 1) {
#pragma unroll
    for (int r = 0; r < 4; ++r) {
      olds[pair][ 0 + lg * 4 + r][li] = o0[r];
      olds[pair][16 + lg * 4 + r][li] = o1[r];
      olds[pair][32 + lg * 4 + r][li] = o2[r];
      olds[pair][48 + lg * 4 + r][li] = o3[r];
    }
  }
  __syncthreads();
  if (half == 0) {
#pragma unroll
    for (int r = 0; r < 4; ++r) {
      o0[r] += olds[pair][ 0 + lg * 4 + r][li];
      o1[r] += olds[pair][16 + lg * 4 + r][li];
      o2[r] += olds[pair][32 + lg * 4 + r][li];
      o3[r] += olds[pair][48 + lg * 4 + r][li];
    }
    float inv = 1.0f / ltot;
    u16* orow = ato + (size_t)(b * 2048 + q) * 1024 + h * 64 + lg * 4;
    *(u32*)(orow +  0) = packbf(o0[0] * inv, o0[1] * inv);
    *(u32*)(orow +  2) = packbf(o0[2] * inv, o0[3] * inv);
    *(u32*)(orow + 16) = packbf(o1[0] * inv, o1[1] * inv);
    *(u32*)(orow + 18) = packbf(o1[2] * inv, o1[3] * inv);
    *(u32*)(orow + 32) = packbf(o2[0] * inv, o2[1] * inv);
    *(u32*)(orow + 34) = packbf(o2[2] * inv, o2[3] * inv);
    *(u32*)(orow + 48) = packbf(o3[0] * inv, o3[1] * inv);
    *(u32*)(orow + 50) = packbf(o3[2] * inv, o3[3] * inv);
  }
}

extern "C" void kernel_launch(void* const* d_in, const int* in_sizes, int n_in,
                              void* d_out, int out_size, void* d_ws, size_t ws_size,
                              hipStream_t stream) {
  const float* x     = (const float*)d_in[0];
  const float* w_qkv = (const float*)d_in[1];
  const float* w_out = (const float*)d_in[2];
  const float* gamma = (const float*)d_in[3];
  const float* beta  = (const float*)d_in[4];
  float* out = (float*)d_out;
  char* ws = (char*)d_ws;

  u16* xn  = (u16*)(ws);              //  8 MB  [4096][1024] bf16
  u16* wq  = (u16*)(ws + 8388608);    //  6 MB  [3072][1024] bf16
  u16* wo  = (u16*)(ws + 14680064);   //  2 MB  [1024][1024] bf16
  u16* qkb = (u16*)(ws + 16777216);   // 16 MB  [4096][2048] bf16 (Q|K)
  u16* vt  = (u16*)(ws + 33554432);   //  8 MB  [2][1024][2048] bf16 (V^T)
  u16* ao  = (u16*)(ws + 41943040);   //  8 MB  [4096][1024] bf16 attn out

  ln_cvt_kernel<<<8192, 256, 0, stream>>>(x, gamma, beta, xn, w_qkv, w_out, wq, wo);
  gemm_bt<0><<<32 * 24, 256, 0, stream>>>(xn, wq, 1024, 24, qkb, vt, nullptr, nullptr);
  attn_kernel<<<32 * 64, 256, 0, stream>>>(qkb, vt, ao);
  gemm_bt<1><<<32 * 8, 256, 0, stream>>>(ao, wo, 1024, 8, nullptr, nullptr, x, out);
}